// Round 8
// baseline (1935.850 us; speedup 1.0000x reference)
//
#include <hip/hip_runtime.h>
#include <hip/hip_bf16.h>

#define NN 100000
#define NE 1600000
#define DIN 512
#define DH 128
#define DOUT 64

#define BSH 9                    // coarse bucket = dst >> 9  (512 nodes)
#define NB ((NN + 511) / 512)    // 196 coarse buckets
#define P1B 512                  // edge-partition blocks for count/write phases
#define EPB ((NE + P1B - 1) / P1B)  // 3125 edges per partition
#define NBA ((NN + 63) / 64)     // 1563 fine buckets (64 nodes) for the spmm kernels

typedef __bf16 bf16_t;
typedef __bf16 bf16x8 __attribute__((ext_vector_type(8)));
typedef float f32x4 __attribute__((ext_vector_type(4)));

__device__ __forceinline__ float bflo(unsigned v) { return __int_as_float(v << 16); }
__device__ __forceinline__ float bfhi(unsigned v) { return __int_as_float(v & 0xffff0000u); }
__device__ __forceinline__ unsigned packbf2(float a, float b) {
    unsigned short ua = __builtin_bit_cast(unsigned short, (bf16_t)a);
    unsigned short ub = __builtin_bit_cast(unsigned short, (bf16_t)b);
    return (unsigned)ua | ((unsigned)ub << 16);
}

// ---------------- weight conversion: w1,w2 -> bf16 ----------------
__global__ __launch_bounds__(256) void convert_w_kernel(const float* __restrict__ w1,
                                                        const float* __restrict__ w2,
                                                        bf16_t* __restrict__ w1b,
                                                        bf16_t* __restrict__ w2b) {
    int i = blockIdx.x * 256 + threadIdx.x;
    if (i < DH * DIN) w1b[i] = (bf16_t)w1[i];
    if (i < DOUT * DH) w2b[i] = (bf16_t)w2[i];
}

// ---------------- GEMM1: h1b[N,128] = bf16(x) @ w1b^T (LDS-staged MFMA) ----------------
__global__ __launch_bounds__(256) void gemm1_mfma(const float* __restrict__ x,
                                                  const bf16_t* __restrict__ w1b,
                                                  bf16_t* __restrict__ h1b) {
    __shared__ __align__(16) char AsB[128 * 128];
    __shared__ __align__(16) char BsB[128 * 128];
    const int t = threadIdx.x;
    const int wv = t >> 6, lane = t & 63;
    const int fr = lane & 15, fq = lane >> 4;
    const int rbase = blockIdx.x * 128;

    f32x4 acc[2][8];
#pragma unroll
    for (int m = 0; m < 2; m++)
#pragma unroll
        for (int n = 0; n < 8; n++) acc[m][n] = (f32x4)0.f;

    for (int k0 = 0; k0 < DIN; k0 += 64) {
#pragma unroll
        for (int j = 0; j < 4; j++) {
            int c = j * 256 + t;
            int row = c >> 3, k8 = c & 7;
            int gr = rbase + row;
            int grc = gr < NN ? gr : NN - 1;
            const float* src = x + (size_t)grc * DIN + k0 + k8 * 8;
            float4 a = *(const float4*)src;
            float4 b = *(const float4*)(src + 4);
            bf16x8 v;
            v[0] = (bf16_t)a.x; v[1] = (bf16_t)a.y; v[2] = (bf16_t)a.z; v[3] = (bf16_t)a.w;
            v[4] = (bf16_t)b.x; v[5] = (bf16_t)b.y; v[6] = (bf16_t)b.z; v[7] = (bf16_t)b.w;
            *(bf16x8*)&AsB[row * 128 + ((k8 ^ (row & 7)) * 16)] = v;
        }
#pragma unroll
        for (int i = 0; i < 4; i++) {
            int c = i * 256 + wv * 64 + lane;
            int cr = c >> 3, sp = c & 7;
            const bf16_t* gsrc = w1b + (size_t)cr * DIN + k0 + ((sp ^ (cr & 7)) * 8);
            __builtin_amdgcn_global_load_lds(
                (const __attribute__((address_space(1))) void*)gsrc,
                (__attribute__((address_space(3))) void*)(BsB + i * 4096 + wv * 1024),
                16, 0, 0);
        }
        __syncthreads();
#pragma unroll
        for (int kk = 0; kk < 2; kk++) {
            bf16x8 af[2];
#pragma unroll
            for (int m = 0; m < 2; m++) {
                int R = wv * 32 + m * 16 + fr;
                af[m] = *(const bf16x8*)&AsB[R * 128 + (((kk * 4 + fq) ^ (R & 7)) * 16)];
            }
#pragma unroll
            for (int n = 0; n < 8; n++) {
                int cr = n * 16 + fr;
                bf16x8 bf = *(const bf16x8*)&BsB[cr * 128 + (((kk * 4 + fq) ^ (cr & 7)) * 16)];
                acc[0][n] = __builtin_amdgcn_mfma_f32_16x16x32_bf16(af[0], bf, acc[0][n], 0, 0, 0);
                acc[1][n] = __builtin_amdgcn_mfma_f32_16x16x32_bf16(af[1], bf, acc[1][n], 0, 0, 0);
            }
        }
        __syncthreads();
    }
#pragma unroll
    for (int m = 0; m < 2; m++)
#pragma unroll
        for (int j = 0; j < 4; j++) {
            int row = rbase + wv * 32 + m * 16 + fq * 4 + j;
            if (row < NN) {
#pragma unroll
                for (int n = 0; n < 8; n++)
                    h1b[(size_t)row * DH + n * 16 + fr] = (bf16_t)acc[m][n][j];
            }
        }
}

// ================= CSR build: two-level counting sort =================
__global__ __launch_bounds__(256) void p1_count(const int* __restrict__ edst,
                                                int* __restrict__ counts) {  // [P1B][256]
    __shared__ int h[NB];
    int blk = blockIdx.x, t = threadIdx.x;
    for (int i = t; i < NB; i += 256) h[i] = 0;
    __syncthreads();
    int e0 = blk * EPB, e1 = min(e0 + EPB, NE);
    for (int e = e0 + t; e < e1; e += 256) atomicAdd(&h[edst[e] >> BSH], 1);
    __syncthreads();
    for (int i = t; i < NB; i += 256) counts[blk * 256 + i] = h[i];
}

__global__ __launch_bounds__(256) void p2_scanblocks(const int* __restrict__ counts,
                                                     int* __restrict__ blockoffs,  // [P1B][256]
                                                     int* __restrict__ btotal) {   // [NB]
    __shared__ int s[512];
    int b = blockIdx.x, t = threadIdx.x;
    int c0 = counts[t * 256 + b];
    int c1 = counts[(t + 256) * 256 + b];
    s[t] = c0; s[t + 256] = c1;
    __syncthreads();
    for (int off = 1; off < 512; off <<= 1) {
        int v0 = (t >= off) ? s[t - off] : 0;
        int v1 = (t + 256 >= off) ? s[t + 256 - off] : 0;
        __syncthreads();
        s[t] += v0; s[t + 256] += v1;
        __syncthreads();
    }
    blockoffs[t * 256 + b] = s[t] - c0;
    blockoffs[(t + 256) * 256 + b] = s[t + 256] - c1;
    if (t == 0) btotal[b] = s[511];
}

__global__ __launch_bounds__(256) void p3_scanbuckets(const int* __restrict__ btotal,
                                                      int* __restrict__ bbase,
                                                      int* __restrict__ rowptr) {
    __shared__ int s[256];
    int t = threadIdx.x;
    int self = (t < NB) ? btotal[t] : 0;
    s[t] = self;
    __syncthreads();
    for (int off = 1; off < 256; off <<= 1) {
        int v = (t >= off) ? s[t - off] : 0;
        __syncthreads();
        s[t] += v;
        __syncthreads();
    }
    if (t < NB) bbase[t] = s[t] - self;
    if (t == 0) rowptr[NN] = NE;
}

__global__ __launch_bounds__(256) void p4_bucketwrite(const int* __restrict__ esrc,
                                                      const int* __restrict__ edst,
                                                      const float* __restrict__ ew,
                                                      const int* __restrict__ blockoffs,
                                                      const int* __restrict__ bbase,
                                                      int2* __restrict__ bsrcw,
                                                      unsigned short* __restrict__ bdst16) {
    __shared__ int cur[NB];
    int blk = blockIdx.x, t = threadIdx.x;
    for (int i = t; i < NB; i += 256) cur[i] = bbase[i] + blockoffs[blk * 256 + i];
    __syncthreads();
    int e0 = blk * EPB, e1 = min(e0 + EPB, NE);
    for (int e = e0 + t; e < e1; e += 256) {
        int d = edst[e];
        int b = d >> BSH;
        int pos = atomicAdd(&cur[b], 1);
        bsrcw[pos] = make_int2(esrc[e], __float_as_int(ew[e]));
        bdst16[pos] = (unsigned short)(d & 511);
    }
}

// p5 now packs dst&511 into bits [25:17] of the src word (src < 2^17).
__global__ __launch_bounds__(256) void p5_bucketsort(const int2* __restrict__ bsrcw,
                                                     const unsigned short* __restrict__ bdst16,
                                                     const int* __restrict__ bbase,
                                                     const int* __restrict__ btotal,
                                                     int2* __restrict__ csr,
                                                     int* __restrict__ rowptr) {
    __shared__ int cnt[512];
    __shared__ int curs[512];
    __shared__ int sc[256];
    int b = blockIdx.x, t = threadIdx.x;
    int base = bbase[b], n = btotal[b];
    int node0 = b << BSH;
    cnt[t] = 0; cnt[t + 256] = 0;
    __syncthreads();
    for (int i = t; i < n; i += 256) atomicAdd(&cnt[bdst16[base + i]], 1);
    __syncthreads();
    int c0 = cnt[2 * t], c1 = cnt[2 * t + 1];
    sc[t] = c0 + c1;
    __syncthreads();
    for (int off = 1; off < 256; off <<= 1) {
        int v = (t >= off) ? sc[t - off] : 0;
        __syncthreads();
        sc[t] += v;
        __syncthreads();
    }
    int e0 = (t > 0) ? sc[t - 1] : 0;
    curs[2 * t] = e0;
    curs[2 * t + 1] = e0 + c0;
    int n0 = node0 + 2 * t, n1 = node0 + 2 * t + 1;
    if (n0 < NN) rowptr[n0] = base + e0;
    if (n1 < NN) rowptr[n1] = base + e0 + c0;
    __syncthreads();
    for (int i = t; i < n; i += 256) {
        int d = (int)bdst16[base + i];
        int2 sw = bsrcw[base + i];
        int p = atomicAdd(&curs[d], 1);
        csr[base + p] = make_int2(sw.x | (d << 17), sw.y);
    }
}

// -------- spmmA: 64-node bucket, flat edge-parallel LDS-atomic agg + relu + MFMA gemm2 --------
__global__ __launch_bounds__(256) void spmmA_fused(const int2* __restrict__ csr,
                                                   const int* __restrict__ rowptr,
                                                   const bf16_t* __restrict__ h1b,
                                                   const bf16_t* __restrict__ w2b,
                                                   bf16_t* __restrict__ h2b) {
    __shared__ float agg[64][132];            // 33 KB, rows 16B-aligned (132*4=528)
    const int t = threadIdx.x;
    const int wv = t >> 6, lane = t & 63;
    const int n0 = blockIdx.x * 64;
    const unsigned* h1w = (const unsigned*)h1b;

    // zero
    {
        float4* az = (float4*)&agg[0][0];
        for (int i = t; i < 64 * 132 / 4; i += 256) az[i] = make_float4(0.f, 0.f, 0.f, 0.f);
    }
    __syncthreads();

    const int est = rowptr[n0];
    const int eend = rowptr[min(n0 + 64, NN)];
    for (int e0 = est + wv * 8; e0 < eend; e0 += 32) {
        int2 r[8];
        float wt[8];
        int dl[8];
#pragma unroll
        for (int j = 0; j < 8; j++) {
            int idx = e0 + j;
            bool ok = idx < eend;
            if (!ok) idx = e0;
            r[j] = csr[idx];
            wt[j] = ok ? __int_as_float(r[j].y) : 0.f;
            dl[j] = (r[j].x >> 17) & 63;
        }
        unsigned v[8];
#pragma unroll
        for (int j = 0; j < 8; j++)
            v[j] = h1w[(size_t)(r[j].x & 0x1FFFF) * 64 + lane];
#pragma unroll
        for (int j = 0; j < 8; j++) {
            atomicAdd(&agg[dl[j]][2 * lane],     wt[j] * bflo(v[j]));
            atomicAdd(&agg[dl[j]][2 * lane + 1], wt[j] * bfhi(v[j]));
        }
    }
    __syncthreads();

    // MFMA epilogue: h2[64x64] = relu(agg[64x128]) @ w2^T. wave = row-tile.
    const int fr = lane & 15, fq = lane >> 4;
    f32x4 acc[4];
#pragma unroll
    for (int n = 0; n < 4; n++) acc[n] = (f32x4)0.f;
#pragma unroll
    for (int kk = 0; kk < 4; kk++) {
        f32x4 a0 = *(const f32x4*)&agg[wv * 16 + fr][kk * 32 + fq * 8];
        f32x4 a1 = *(const f32x4*)&agg[wv * 16 + fr][kk * 32 + fq * 8 + 4];
        bf16x8 af;
        af[0] = (bf16_t)fmaxf(a0[0], 0.f); af[1] = (bf16_t)fmaxf(a0[1], 0.f);
        af[2] = (bf16_t)fmaxf(a0[2], 0.f); af[3] = (bf16_t)fmaxf(a0[3], 0.f);
        af[4] = (bf16_t)fmaxf(a1[0], 0.f); af[5] = (bf16_t)fmaxf(a1[1], 0.f);
        af[6] = (bf16_t)fmaxf(a1[2], 0.f); af[7] = (bf16_t)fmaxf(a1[3], 0.f);
#pragma unroll
        for (int n = 0; n < 4; n++) {
            bf16x8 bf = *(const bf16x8*)(w2b + (size_t)(n * 16 + fr) * DH + kk * 32 + fq * 8);
            acc[n] = __builtin_amdgcn_mfma_f32_16x16x32_bf16(af, bf, acc[n], 0, 0, 0);
        }
    }
#pragma unroll
    for (int j = 0; j < 4; j++) {
        int node = n0 + wv * 16 + fq * 4 + j;
        if (node < NN) {
#pragma unroll
            for (int n = 0; n < 4; n++)
                h2b[(size_t)node * DOUT + n * 16 + fr] = (bf16_t)acc[n][j];
        }
    }
}

// -------- spmmB: 64-node bucket, flat edge-parallel LDS-atomic agg + fused log_softmax --------
__global__ __launch_bounds__(256) void spmmB_ls(const int2* __restrict__ csr,
                                                const int* __restrict__ rowptr,
                                                const bf16_t* __restrict__ h2b,
                                                float* __restrict__ outp) {
    __shared__ float agg[64][66];             // 16.9 KB
    const int t = threadIdx.x;
    const int hw = t >> 5, lc = t & 31;       // 8 half-waves
    const int n0 = blockIdx.x * 64;
    const unsigned* h2w = (const unsigned*)h2b;

    {
        float2* az = (float2*)&agg[0][0];
        for (int i = t; i < 64 * 66 / 2; i += 256) az[i] = make_float2(0.f, 0.f);
    }
    __syncthreads();

    const int est = rowptr[n0];
    const int eend = rowptr[min(n0 + 64, NN)];
    for (int e0 = est + hw * 8; e0 < eend; e0 += 64) {
        int2 r[8];
        float wt[8];
        int dl[8];
#pragma unroll
        for (int j = 0; j < 8; j++) {
            int idx = e0 + j;
            bool ok = idx < eend;
            if (!ok) idx = e0;
            r[j] = csr[idx];
            wt[j] = ok ? __int_as_float(r[j].y) : 0.f;
            dl[j] = (r[j].x >> 17) & 63;
        }
        unsigned v[8];
#pragma unroll
        for (int j = 0; j < 8; j++)
            v[j] = h2w[(size_t)(r[j].x & 0x1FFFF) * 32 + lc];
#pragma unroll
        for (int j = 0; j < 8; j++) {
            atomicAdd(&agg[dl[j]][2 * lc],     wt[j] * bflo(v[j]));
            atomicAdd(&agg[dl[j]][2 * lc + 1], wt[j] * bfhi(v[j]));
        }
    }
    __syncthreads();

    // per-node log_softmax: wave wv owns nodes wv*16..wv*16+15
    const int wv = t >> 6, lane = t & 63;
#pragma unroll 4
    for (int i = 0; i < 16; i++) {
        int row = wv * 16 + i;
        int node = n0 + row;
        if (node >= NN) break;
        float v = agg[row][lane];
        float m = v;
#pragma unroll
        for (int off = 32; off >= 1; off >>= 1) m = fmaxf(m, __shfl_xor(m, off));
        float s = expf(v - m);
#pragma unroll
        for (int off = 32; off >= 1; off >>= 1) s += __shfl_xor(s, off);
        outp[(size_t)node * DOUT + lane] = (v - m) - logf(s);
    }
}

extern "C" void kernel_launch(void* const* d_in, const int* in_sizes, int n_in,
                              void* d_out, int out_size, void* d_ws, size_t ws_size,
                              hipStream_t stream) {
    const float* x  = (const float*)d_in[0];
    const float* w1 = (const float*)d_in[1];
    const float* w2 = (const float*)d_in[2];
    const int* esrc = (const int*)d_in[3];
    const int* edst = (const int*)d_in[4];
    const float* ew = (const float*)d_in[5];
    float* out = (float*)d_out;

    char* ws = (char*)d_ws;
    size_t off = 0;
    auto alloc = [&](size_t bytes) {
        void* p = ws + off;
        off = (off + bytes + 255) & ~(size_t)255;
        return p;
    };
    bf16_t* h1b      = (bf16_t*)alloc((size_t)NN * DH * 2);      // 25.6 MB
    bf16_t* h2b      = (bf16_t*)alloc((size_t)NN * DOUT * 2);    // 12.8 MB
    bf16_t* w1b      = (bf16_t*)alloc((size_t)DH * DIN * 2);
    bf16_t* w2b      = (bf16_t*)alloc((size_t)DOUT * DH * 2);
    int2*   csr      = (int2*)alloc((size_t)(NE + 8) * 8);       // 12.8 MB
    int2*   bsrcw    = (int2*)alloc((size_t)NE * 8);             // 12.8 MB
    unsigned short* bdst16 = (unsigned short*)alloc((size_t)NE * 2);
    int*    rowptr   = (int*)alloc((size_t)(NN + 1) * 4);
    int*    counts   = (int*)alloc((size_t)P1B * 256 * 4);
    int*    blockoffs= (int*)alloc((size_t)P1B * 256 * 4);
    int*    btotal   = (int*)alloc((size_t)256 * 4);
    int*    bbase    = (int*)alloc((size_t)256 * 4);

    // 0. weights -> bf16
    convert_w_kernel<<<(DH * DIN + 255) / 256, 256, 0, stream>>>(w1, w2, w1b, w2b);
    // 1. h1b = bf16(x) @ w1b^T
    gemm1_mfma<<<(NN + 127) / 128, 256, 0, stream>>>(x, w1b, h1b);
    // 2. CSR build (dst-sorted; src word carries dst&511 in bits [25:17])
    p1_count<<<P1B, 256, 0, stream>>>(edst, counts);
    p2_scanblocks<<<NB, 256, 0, stream>>>(counts, blockoffs, btotal);
    p3_scanbuckets<<<1, 256, 0, stream>>>(btotal, bbase, rowptr);
    p4_bucketwrite<<<P1B, 256, 0, stream>>>(esrc, edst, ew, blockoffs, bbase, bsrcw, bdst16);
    p5_bucketsort<<<NB, 256, 0, stream>>>(bsrcw, bdst16, bbase, btotal, csr, rowptr);
    // 3+4. h2b = relu(SpMM(h1b)) @ w2^T   (bucket-LDS edge-parallel + MFMA)
    spmmA_fused<<<NBA, 256, 0, stream>>>(csr, rowptr, h1b, w2b, h2b);
    // 5. out = log_softmax(SpMM(h2b))
    spmmB_ls<<<NBA, 256, 0, stream>>>(csr, rowptr, h2b, out);
}

// Round 9
// 260.668 us; speedup vs baseline: 7.4265x; 7.4265x over previous
//
#include <hip/hip_runtime.h>
#include <hip/hip_bf16.h>

#define NN 100000
#define NE 1600000
#define DIN 512
#define DH 128
#define DOUT 64

#define BSH 9                    // bucket = dst >> 9  (512 nodes per bucket)
#define NB ((NN + 511) / 512)    // 196 buckets
#define P1B 512                  // edge-partition blocks for count/write phases
#define EPB ((NE + P1B - 1) / P1B)  // 3125 edges per partition

typedef __bf16 bf16_t;
typedef __bf16 bf16x8 __attribute__((ext_vector_type(8)));
typedef float f32x4 __attribute__((ext_vector_type(4)));

__device__ __forceinline__ float bflo(unsigned v) { return __int_as_float(v << 16); }
__device__ __forceinline__ float bfhi(unsigned v) { return __int_as_float(v & 0xffff0000u); }
__device__ __forceinline__ unsigned packbf2(float a, float b) {
    unsigned short ua = __builtin_bit_cast(unsigned short, (bf16_t)a);
    unsigned short ub = __builtin_bit_cast(unsigned short, (bf16_t)b);
    return (unsigned)ua | ((unsigned)ub << 16);
}

// ---------------- weight conversion: w1,w2 -> bf16 ----------------
__global__ __launch_bounds__(256) void convert_w_kernel(const float* __restrict__ w1,
                                                        const float* __restrict__ w2,
                                                        bf16_t* __restrict__ w1b,
                                                        bf16_t* __restrict__ w2b) {
    int i = blockIdx.x * 256 + threadIdx.x;
    if (i < DH * DIN) w1b[i] = (bf16_t)w1[i];
    if (i < DOUT * DH) w2b[i] = (bf16_t)w2[i];
}

// ---------------- GEMM1: h1b[N,128] = bf16(x) @ w1b^T (LDS-staged MFMA) ----------------
__global__ __launch_bounds__(256) void gemm1_mfma(const float* __restrict__ x,
                                                  const bf16_t* __restrict__ w1b,
                                                  bf16_t* __restrict__ h1b) {
    __shared__ __align__(16) char AsB[128 * 128];
    __shared__ __align__(16) char BsB[128 * 128];
    const int t = threadIdx.x;
    const int wv = t >> 6, lane = t & 63;
    const int fr = lane & 15, fq = lane >> 4;
    const int rbase = blockIdx.x * 128;

    f32x4 acc[2][8];
#pragma unroll
    for (int m = 0; m < 2; m++)
#pragma unroll
        for (int n = 0; n < 8; n++) acc[m][n] = (f32x4)0.f;

    for (int k0 = 0; k0 < DIN; k0 += 64) {
#pragma unroll
        for (int j = 0; j < 4; j++) {
            int c = j * 256 + t;
            int row = c >> 3, k8 = c & 7;
            int gr = rbase + row;
            int grc = gr < NN ? gr : NN - 1;
            const float* src = x + (size_t)grc * DIN + k0 + k8 * 8;
            float4 a = *(const float4*)src;
            float4 b = *(const float4*)(src + 4);
            bf16x8 v;
            v[0] = (bf16_t)a.x; v[1] = (bf16_t)a.y; v[2] = (bf16_t)a.z; v[3] = (bf16_t)a.w;
            v[4] = (bf16_t)b.x; v[5] = (bf16_t)b.y; v[6] = (bf16_t)b.z; v[7] = (bf16_t)b.w;
            *(bf16x8*)&AsB[row * 128 + ((k8 ^ (row & 7)) * 16)] = v;
        }
#pragma unroll
        for (int i = 0; i < 4; i++) {
            int c = i * 256 + wv * 64 + lane;
            int cr = c >> 3, sp = c & 7;
            const bf16_t* gsrc = w1b + (size_t)cr * DIN + k0 + ((sp ^ (cr & 7)) * 8);
            __builtin_amdgcn_global_load_lds(
                (const __attribute__((address_space(1))) void*)gsrc,
                (__attribute__((address_space(3))) void*)(BsB + i * 4096 + wv * 1024),
                16, 0, 0);
        }
        __syncthreads();
#pragma unroll
        for (int kk = 0; kk < 2; kk++) {
            bf16x8 af[2];
#pragma unroll
            for (int m = 0; m < 2; m++) {
                int R = wv * 32 + m * 16 + fr;
                af[m] = *(const bf16x8*)&AsB[R * 128 + (((kk * 4 + fq) ^ (R & 7)) * 16)];
            }
#pragma unroll
            for (int n = 0; n < 8; n++) {
                int cr = n * 16 + fr;
                bf16x8 bf = *(const bf16x8*)&BsB[cr * 128 + (((kk * 4 + fq) ^ (cr & 7)) * 16)];
                acc[0][n] = __builtin_amdgcn_mfma_f32_16x16x32_bf16(af[0], bf, acc[0][n], 0, 0, 0);
                acc[1][n] = __builtin_amdgcn_mfma_f32_16x16x32_bf16(af[1], bf, acc[1][n], 0, 0, 0);
            }
        }
        __syncthreads();
    }
#pragma unroll
    for (int m = 0; m < 2; m++)
#pragma unroll
        for (int j = 0; j < 4; j++) {
            int row = rbase + wv * 32 + m * 16 + fq * 4 + j;
            if (row < NN) {
#pragma unroll
                for (int n = 0; n < 8; n++)
                    h1b[(size_t)row * DH + n * 16 + fr] = (bf16_t)acc[m][n][j];
            }
        }
}

// ================= CSR build: two-level counting sort =================
__global__ __launch_bounds__(256) void p1_count(const int* __restrict__ edst,
                                                int* __restrict__ counts) {  // [P1B][256]
    __shared__ int h[NB];
    int blk = blockIdx.x, t = threadIdx.x;
    for (int i = t; i < NB; i += 256) h[i] = 0;
    __syncthreads();
    int e0 = blk * EPB, e1 = min(e0 + EPB, NE);
    for (int e = e0 + t; e < e1; e += 256) atomicAdd(&h[edst[e] >> BSH], 1);
    __syncthreads();
    for (int i = t; i < NB; i += 256) counts[blk * 256 + i] = h[i];
}

__global__ __launch_bounds__(256) void p2_scanblocks(const int* __restrict__ counts,
                                                     int* __restrict__ blockoffs,  // [P1B][256]
                                                     int* __restrict__ btotal) {   // [NB]
    __shared__ int s[512];
    int b = blockIdx.x, t = threadIdx.x;
    int c0 = counts[t * 256 + b];
    int c1 = counts[(t + 256) * 256 + b];
    s[t] = c0; s[t + 256] = c1;
    __syncthreads();
    for (int off = 1; off < 512; off <<= 1) {
        int v0 = (t >= off) ? s[t - off] : 0;
        int v1 = (t + 256 >= off) ? s[t + 256 - off] : 0;
        __syncthreads();
        s[t] += v0; s[t + 256] += v1;
        __syncthreads();
    }
    blockoffs[t * 256 + b] = s[t] - c0;
    blockoffs[(t + 256) * 256 + b] = s[t + 256] - c1;
    if (t == 0) btotal[b] = s[511];
}

__global__ __launch_bounds__(256) void p3_scanbuckets(const int* __restrict__ btotal,
                                                      int* __restrict__ bbase,
                                                      int* __restrict__ rowptr) {
    __shared__ int s[256];
    int t = threadIdx.x;
    int self = (t < NB) ? btotal[t] : 0;
    s[t] = self;
    __syncthreads();
    for (int off = 1; off < 256; off <<= 1) {
        int v = (t >= off) ? s[t - off] : 0;
        __syncthreads();
        s[t] += v;
        __syncthreads();
    }
    if (t < NB) bbase[t] = s[t] - self;
    if (t == 0) rowptr[NN] = NE;
}

__global__ __launch_bounds__(256) void p4_bucketwrite(const int* __restrict__ esrc,
                                                      const int* __restrict__ edst,
                                                      const float* __restrict__ ew,
                                                      const int* __restrict__ blockoffs,
                                                      const int* __restrict__ bbase,
                                                      int2* __restrict__ bsrcw,
                                                      unsigned short* __restrict__ bdst16) {
    __shared__ int cur[NB];
    int blk = blockIdx.x, t = threadIdx.x;
    for (int i = t; i < NB; i += 256) cur[i] = bbase[i] + blockoffs[blk * 256 + i];
    __syncthreads();
    int e0 = blk * EPB, e1 = min(e0 + EPB, NE);
    for (int e = e0 + t; e < e1; e += 256) {
        int d = edst[e];
        int b = d >> BSH;
        int pos = atomicAdd(&cur[b], 1);
        bsrcw[pos] = make_int2(esrc[e], __float_as_int(ew[e]));
        bdst16[pos] = (unsigned short)(d & 511);
    }
}

__global__ __launch_bounds__(256) void p5_bucketsort(const int2* __restrict__ bsrcw,
                                                     const unsigned short* __restrict__ bdst16,
                                                     const int* __restrict__ bbase,
                                                     const int* __restrict__ btotal,
                                                     int2* __restrict__ csr,
                                                     int* __restrict__ rowptr) {
    __shared__ int cnt[512];
    __shared__ int curs[512];
    __shared__ int sc[256];
    int b = blockIdx.x, t = threadIdx.x;
    int base = bbase[b], n = btotal[b];
    int node0 = b << BSH;
    cnt[t] = 0; cnt[t + 256] = 0;
    __syncthreads();
    for (int i = t; i < n; i += 256) atomicAdd(&cnt[bdst16[base + i]], 1);
    __syncthreads();
    int c0 = cnt[2 * t], c1 = cnt[2 * t + 1];
    sc[t] = c0 + c1;
    __syncthreads();
    for (int off = 1; off < 256; off <<= 1) {
        int v = (t >= off) ? sc[t - off] : 0;
        __syncthreads();
        sc[t] += v;
        __syncthreads();
    }
    int e0 = (t > 0) ? sc[t - 1] : 0;
    curs[2 * t] = e0;
    curs[2 * t + 1] = e0 + c0;
    int n0 = node0 + 2 * t, n1 = node0 + 2 * t + 1;
    if (n0 < NN) rowptr[n0] = base + e0;
    if (n1 < NN) rowptr[n1] = base + e0 + c0;
    __syncthreads();
    for (int i = t; i < n; i += 256) {
        unsigned short d = bdst16[base + i];
        int2 sw = bsrcw[base + i];
        int p = atomicAdd(&curs[d], 1);
        csr[base + p] = sw;
    }
}

// ---------------- fused: spmm128 gather (8-deep ILP) + relu + MFMA matvec -> h2b ----------------
__global__ __launch_bounds__(256) void spmm1_fused(const int2* __restrict__ csr,
                                                   const int* __restrict__ rowptr,
                                                   const bf16_t* __restrict__ h1b,
                                                   const bf16_t* __restrict__ w2b,
                                                   bf16_t* __restrict__ h2b) {
    __shared__ unsigned aggs[16][68];   // [node][k-pair], stride 68 dwords
    const int t = threadIdx.x;
    const int wv = t >> 6, lane = t & 63;
    const int nb = blockIdx.x * 16;     // NN % 16 == 0
    const unsigned* h1w = (const unsigned*)h1b;

#pragma unroll
    for (int q = 0; q < 4; q++) {
        int n = nb + wv * 4 + q;
        int st = rowptr[n], end = rowptr[n + 1];
        float ax = 0.f, ay = 0.f;
        for (int i = st; i < end; i += 8) {
            int2 e[8];
            float w[8];
#pragma unroll
            for (int j = 0; j < 8; j++) {
                int idx = i + j;
                bool ok = idx < end;
                e[j] = csr[ok ? idx : st];
                w[j] = ok ? __int_as_float(e[j].y) : 0.f;
            }
            unsigned v[8];
#pragma unroll
            for (int j = 0; j < 8; j++)
                v[j] = h1w[(size_t)e[j].x * 64 + lane];
#pragma unroll
            for (int j = 0; j < 8; j++) {
                ax = fmaf(w[j], bflo(v[j]), ax);
                ay = fmaf(w[j], bfhi(v[j]), ay);
            }
        }
        ax = fmaxf(ax, 0.f); ay = fmaxf(ay, 0.f);     // relu
        aggs[wv * 4 + q][lane] = packbf2(ax, ay);
    }
    __syncthreads();

    // MFMA: A = aggs[16][128] (LDS), B = w2 rows wv*16..wv*16+15 (L2)
    const int fr = lane & 15, fq = lane >> 4;
    f32x4 acc = (f32x4)0.f;
    const bf16_t* pb = w2b + (size_t)(wv * 16 + fr) * DH + fq * 8;
    const bf16_t* arow = (const bf16_t*)aggs[fr];
#pragma unroll
    for (int kk = 0; kk < 4; kk++) {
        bf16x8 af = *(const bf16x8*)&arow[kk * 32 + fq * 8];
        bf16x8 bf = *(const bf16x8*)(pb + kk * 32);
        acc = __builtin_amdgcn_mfma_f32_16x16x32_bf16(af, bf, acc, 0, 0, 0);
    }
#pragma unroll
    for (int j = 0; j < 4; j++) {
        int node = nb + fq * 4 + j;
        h2b[(size_t)node * DOUT + wv * 16 + fr] = (bf16_t)acc[j];
    }
}

// ---------------- SpMM-CSR d=64 + fused log_softmax (8 edges in flight, 4/half-wave) ----------------
__global__ __launch_bounds__(256) void spmm64_ls_kernel(const int2* __restrict__ csr,
                                                        const int* __restrict__ rowptr,
                                                        const bf16_t* __restrict__ h2b,
                                                        float* __restrict__ outp) {
    int n = blockIdx.x * 4 + (threadIdx.x >> 6);
    int lane = threadIdx.x & 63;
    int half = lane >> 5, lc = lane & 31;
    if (n >= NN) return;
    const unsigned* h2w = (const unsigned*)h2b;
    int st = rowptr[n], end = rowptr[n + 1];
    float ax = 0.f, ay = 0.f;
    for (int i = st; i < end; i += 8) {
        int ib = i + half * 4;          // this half-wave's 4 edges
        int2 e[4];
        float w[4];
#pragma unroll
        for (int j = 0; j < 4; j++) {
            int idx = ib + j;
            bool ok = idx < end;
            e[j] = csr[ok ? idx : st];
            w[j] = ok ? __int_as_float(e[j].y) : 0.f;
        }
        unsigned v[4];
#pragma unroll
        for (int j = 0; j < 4; j++)
            v[j] = h2w[(size_t)e[j].x * 32 + lc];
#pragma unroll
        for (int j = 0; j < 4; j++) {
            ax = fmaf(w[j], bflo(v[j]), ax);
            ay = fmaf(w[j], bfhi(v[j]), ay);
        }
    }
    ax += __shfl_xor(ax, 32);
    ay += __shfl_xor(ay, 32);
    float m = fmaxf(ax, ay);
#pragma unroll
    for (int off = 16; off >= 1; off >>= 1) m = fmaxf(m, __shfl_xor(m, off));
    float s = expf(ax - m) + expf(ay - m);
#pragma unroll
    for (int off = 16; off >= 1; off >>= 1) s += __shfl_xor(s, off);
    float ls = logf(s);
    if (half == 0) {
        float2 o = make_float2(ax - m - ls, ay - m - ls);
        *(float2*)&outp[(size_t)n * DOUT + lc * 2] = o;
    }
}

extern "C" void kernel_launch(void* const* d_in, const int* in_sizes, int n_in,
                              void* d_out, int out_size, void* d_ws, size_t ws_size,
                              hipStream_t stream) {
    const float* x  = (const float*)d_in[0];
    const float* w1 = (const float*)d_in[1];
    const float* w2 = (const float*)d_in[2];
    const int* esrc = (const int*)d_in[3];
    const int* edst = (const int*)d_in[4];
    const float* ew = (const float*)d_in[5];
    float* out = (float*)d_out;

    char* ws = (char*)d_ws;
    size_t off = 0;
    auto alloc = [&](size_t bytes) {
        void* p = ws + off;
        off = (off + bytes + 255) & ~(size_t)255;
        return p;
    };
    bf16_t* h1b      = (bf16_t*)alloc((size_t)NN * DH * 2);      // 25.6 MB
    bf16_t* h2b      = (bf16_t*)alloc((size_t)NN * DOUT * 2);    // 12.8 MB
    bf16_t* w1b      = (bf16_t*)alloc((size_t)DH * DIN * 2);
    bf16_t* w2b      = (bf16_t*)alloc((size_t)DOUT * DH * 2);
    int2*   csr      = (int2*)alloc((size_t)(NE + 8) * 8);       // 12.8 MB
    int2*   bsrcw    = (int2*)alloc((size_t)NE * 8);             // 12.8 MB
    unsigned short* bdst16 = (unsigned short*)alloc((size_t)NE * 2);
    int*    rowptr   = (int*)alloc((size_t)(NN + 1) * 4);
    int*    counts   = (int*)alloc((size_t)P1B * 256 * 4);
    int*    blockoffs= (int*)alloc((size_t)P1B * 256 * 4);
    int*    btotal   = (int*)alloc((size_t)256 * 4);
    int*    bbase    = (int*)alloc((size_t)256 * 4);

    // 0. weights -> bf16
    convert_w_kernel<<<(DH * DIN + 255) / 256, 256, 0, stream>>>(w1, w2, w1b, w2b);
    // 1. h1b = bf16(x) @ w1b^T   (LDS-staged MFMA)
    gemm1_mfma<<<(NN + 127) / 128, 256, 0, stream>>>(x, w1b, h1b);
    // 2. CSR build
    p1_count<<<P1B, 256, 0, stream>>>(edst, counts);
    p2_scanblocks<<<NB, 256, 0, stream>>>(counts, blockoffs, btotal);
    p3_scanbuckets<<<1, 256, 0, stream>>>(btotal, bbase, rowptr);
    p4_bucketwrite<<<P1B, 256, 0, stream>>>(esrc, edst, ew, blockoffs, bbase, bsrcw, bdst16);
    p5_bucketsort<<<NB, 256, 0, stream>>>(bsrcw, bdst16, bbase, btotal, csr, rowptr);
    // 3+4. h2b = relu(SpMM(h1b)) @ w2^T   (fused, MFMA epilogue)
    spmm1_fused<<<NN / 16, 256, 0, stream>>>(csr, rowptr, h1b, w2b, h2b);
    // 5. out = log_softmax(SpMM(h2b))
    spmm64_ls_kernel<<<(NN + 3) / 4, 256, 0, stream>>>(csr, rowptr, h2b, out);
}

// Round 10
// 256.377 us; speedup vs baseline: 7.5508x; 1.0167x over previous
//
#include <hip/hip_runtime.h>
#include <hip/hip_bf16.h>

#define NN 100000
#define NE 1600000
#define DIN 512
#define DH 128
#define DOUT 64

#define BSH 9                    // bucket = dst >> 9  (512 nodes per bucket)
#define NB ((NN + 511) / 512)    // 196 buckets
#define P1B 512                  // edge-partition blocks for count/write phases
#define EPB ((NE + P1B - 1) / P1B)  // 3125 edges per partition

typedef __bf16 bf16_t;
typedef __bf16 bf16x8 __attribute__((ext_vector_type(8)));
typedef float f32x4 __attribute__((ext_vector_type(4)));

__device__ __forceinline__ float bflo(unsigned v) { return __int_as_float(v << 16); }
__device__ __forceinline__ float bfhi(unsigned v) { return __int_as_float(v & 0xffff0000u); }
__device__ __forceinline__ unsigned packbf2(float a, float b) {
    unsigned short ua = __builtin_bit_cast(unsigned short, (bf16_t)a);
    unsigned short ub = __builtin_bit_cast(unsigned short, (bf16_t)b);
    return (unsigned)ua | ((unsigned)ub << 16);
}

// ---------------- weight conversion: w1,w2 -> bf16 ----------------
__global__ __launch_bounds__(256) void convert_w_kernel(const float* __restrict__ w1,
                                                        const float* __restrict__ w2,
                                                        bf16_t* __restrict__ w1b,
                                                        bf16_t* __restrict__ w2b) {
    int i = blockIdx.x * 256 + threadIdx.x;
    if (i < DH * DIN) w1b[i] = (bf16_t)w1[i];
    if (i < DOUT * DH) w2b[i] = (bf16_t)w2[i];
}

// ---------------- GEMM1: h1b[N,128] = bf16(x) @ w1b^T (LDS-staged MFMA) ----------------
__global__ __launch_bounds__(256) void gemm1_mfma(const float* __restrict__ x,
                                                  const bf16_t* __restrict__ w1b,
                                                  bf16_t* __restrict__ h1b) {
    __shared__ __align__(16) char AsB[128 * 128];
    __shared__ __align__(16) char BsB[128 * 128];
    const int t = threadIdx.x;
    const int wv = t >> 6, lane = t & 63;
    const int fr = lane & 15, fq = lane >> 4;
    const int rbase = blockIdx.x * 128;

    f32x4 acc[2][8];
#pragma unroll
    for (int m = 0; m < 2; m++)
#pragma unroll
        for (int n = 0; n < 8; n++) acc[m][n] = (f32x4)0.f;

    for (int k0 = 0; k0 < DIN; k0 += 64) {
#pragma unroll
        for (int j = 0; j < 4; j++) {
            int c = j * 256 + t;
            int row = c >> 3, k8 = c & 7;
            int gr = rbase + row;
            int grc = gr < NN ? gr : NN - 1;
            const float* src = x + (size_t)grc * DIN + k0 + k8 * 8;
            float4 a = *(const float4*)src;
            float4 b = *(const float4*)(src + 4);
            bf16x8 v;
            v[0] = (bf16_t)a.x; v[1] = (bf16_t)a.y; v[2] = (bf16_t)a.z; v[3] = (bf16_t)a.w;
            v[4] = (bf16_t)b.x; v[5] = (bf16_t)b.y; v[6] = (bf16_t)b.z; v[7] = (bf16_t)b.w;
            *(bf16x8*)&AsB[row * 128 + ((k8 ^ (row & 7)) * 16)] = v;
        }
#pragma unroll
        for (int i = 0; i < 4; i++) {
            int c = i * 256 + wv * 64 + lane;
            int cr = c >> 3, sp = c & 7;
            const bf16_t* gsrc = w1b + (size_t)cr * DIN + k0 + ((sp ^ (cr & 7)) * 8);
            __builtin_amdgcn_global_load_lds(
                (const __attribute__((address_space(1))) void*)gsrc,
                (__attribute__((address_space(3))) void*)(BsB + i * 4096 + wv * 1024),
                16, 0, 0);
        }
        __syncthreads();
#pragma unroll
        for (int kk = 0; kk < 2; kk++) {
            bf16x8 af[2];
#pragma unroll
            for (int m = 0; m < 2; m++) {
                int R = wv * 32 + m * 16 + fr;
                af[m] = *(const bf16x8*)&AsB[R * 128 + (((kk * 4 + fq) ^ (R & 7)) * 16)];
            }
#pragma unroll
            for (int n = 0; n < 8; n++) {
                int cr = n * 16 + fr;
                bf16x8 bf = *(const bf16x8*)&BsB[cr * 128 + (((kk * 4 + fq) ^ (cr & 7)) * 16)];
                acc[0][n] = __builtin_amdgcn_mfma_f32_16x16x32_bf16(af[0], bf, acc[0][n], 0, 0, 0);
                acc[1][n] = __builtin_amdgcn_mfma_f32_16x16x32_bf16(af[1], bf, acc[1][n], 0, 0, 0);
            }
        }
        __syncthreads();
    }
#pragma unroll
    for (int m = 0; m < 2; m++)
#pragma unroll
        for (int j = 0; j < 4; j++) {
            int row = rbase + wv * 32 + m * 16 + fq * 4 + j;
            if (row < NN) {
#pragma unroll
                for (int n = 0; n < 8; n++)
                    h1b[(size_t)row * DH + n * 16 + fr] = (bf16_t)acc[m][n][j];
            }
        }
}

// ================= CSR build: two-level counting sort =================
__global__ __launch_bounds__(256) void p1_count(const int* __restrict__ edst,
                                                int* __restrict__ counts) {  // [P1B][256]
    __shared__ int h[NB];
    int blk = blockIdx.x, t = threadIdx.x;
    for (int i = t; i < NB; i += 256) h[i] = 0;
    __syncthreads();
    int e0 = blk * EPB, e1 = min(e0 + EPB, NE);
    for (int e = e0 + t; e < e1; e += 256) atomicAdd(&h[edst[e] >> BSH], 1);
    __syncthreads();
    for (int i = t; i < NB; i += 256) counts[blk * 256 + i] = h[i];
}

__global__ __launch_bounds__(256) void p2_scanblocks(const int* __restrict__ counts,
                                                     int* __restrict__ blockoffs,  // [P1B][256]
                                                     int* __restrict__ btotal) {   // [NB]
    __shared__ int s[512];
    int b = blockIdx.x, t = threadIdx.x;
    int c0 = counts[t * 256 + b];
    int c1 = counts[(t + 256) * 256 + b];
    s[t] = c0; s[t + 256] = c1;
    __syncthreads();
    for (int off = 1; off < 512; off <<= 1) {
        int v0 = (t >= off) ? s[t - off] : 0;
        int v1 = (t + 256 >= off) ? s[t + 256 - off] : 0;
        __syncthreads();
        s[t] += v0; s[t + 256] += v1;
        __syncthreads();
    }
    blockoffs[t * 256 + b] = s[t] - c0;
    blockoffs[(t + 256) * 256 + b] = s[t + 256] - c1;
    if (t == 0) btotal[b] = s[511];
}

__global__ __launch_bounds__(256) void p3_scanbuckets(const int* __restrict__ btotal,
                                                      int* __restrict__ bbase,
                                                      int* __restrict__ rowptr) {
    __shared__ int s[256];
    int t = threadIdx.x;
    int self = (t < NB) ? btotal[t] : 0;
    s[t] = self;
    __syncthreads();
    for (int off = 1; off < 256; off <<= 1) {
        int v = (t >= off) ? s[t - off] : 0;
        __syncthreads();
        s[t] += v;
        __syncthreads();
    }
    if (t < NB) bbase[t] = s[t] - self;
    if (t == 0) rowptr[NN] = NE;
}

__global__ __launch_bounds__(256) void p4_bucketwrite(const int* __restrict__ esrc,
                                                      const int* __restrict__ edst,
                                                      const float* __restrict__ ew,
                                                      const int* __restrict__ blockoffs,
                                                      const int* __restrict__ bbase,
                                                      int2* __restrict__ bsrcw,
                                                      unsigned short* __restrict__ bdst16) {
    __shared__ int cur[NB];
    int blk = blockIdx.x, t = threadIdx.x;
    for (int i = t; i < NB; i += 256) cur[i] = bbase[i] + blockoffs[blk * 256 + i];
    __syncthreads();
    int e0 = blk * EPB, e1 = min(e0 + EPB, NE);
    for (int e = e0 + t; e < e1; e += 256) {
        int d = edst[e];
        int b = d >> BSH;
        int pos = atomicAdd(&cur[b], 1);
        bsrcw[pos] = make_int2(esrc[e], __float_as_int(ew[e]));
        bdst16[pos] = (unsigned short)(d & 511);
    }
}

__global__ __launch_bounds__(256) void p5_bucketsort(const int2* __restrict__ bsrcw,
                                                     const unsigned short* __restrict__ bdst16,
                                                     const int* __restrict__ bbase,
                                                     const int* __restrict__ btotal,
                                                     int2* __restrict__ csr,
                                                     int* __restrict__ rowptr) {
    __shared__ int cnt[512];
    __shared__ int curs[512];
    __shared__ int sc[256];
    int b = blockIdx.x, t = threadIdx.x;
    int base = bbase[b], n = btotal[b];
    int node0 = b << BSH;
    cnt[t] = 0; cnt[t + 256] = 0;
    __syncthreads();
    for (int i = t; i < n; i += 256) atomicAdd(&cnt[bdst16[base + i]], 1);
    __syncthreads();
    int c0 = cnt[2 * t], c1 = cnt[2 * t + 1];
    sc[t] = c0 + c1;
    __syncthreads();
    for (int off = 1; off < 256; off <<= 1) {
        int v = (t >= off) ? sc[t - off] : 0;
        __syncthreads();
        sc[t] += v;
        __syncthreads();
    }
    int e0 = (t > 0) ? sc[t - 1] : 0;
    curs[2 * t] = e0;
    curs[2 * t + 1] = e0 + c0;
    int n0 = node0 + 2 * t, n1 = node0 + 2 * t + 1;
    if (n0 < NN) rowptr[n0] = base + e0;
    if (n1 < NN) rowptr[n1] = base + e0 + c0;
    __syncthreads();
    for (int i = t; i < n; i += 256) {
        unsigned short d = bdst16[base + i];
        int2 sw = bsrcw[base + i];
        int p = atomicAdd(&curs[d], 1);
        csr[base + p] = sw;
    }
}

// ---- fused: spmm128 gather (uint2 lanes: 2 rows/wave-load, 16 edges in flight) + relu + MFMA ----
__global__ __launch_bounds__(256) void spmm1_fused(const int2* __restrict__ csr,
                                                   const int* __restrict__ rowptr,
                                                   const bf16_t* __restrict__ h1b,
                                                   const bf16_t* __restrict__ w2b,
                                                   bf16_t* __restrict__ h2b) {
    __shared__ unsigned aggs[16][68];   // [node][k-pair], stride 68 dwords
    const int t = threadIdx.x;
    const int wv = t >> 6, lane = t & 63;
    const int half = lane >> 5, lc = lane & 31;
    const int nb = blockIdx.x * 16;     // NN % 16 == 0
    const uint2* h1u = (const uint2*)h1b;   // row = 32 uint2 (256 B)

#pragma unroll
    for (int q = 0; q < 4; q++) {
        int n = nb + wv * 4 + q;
        int st = rowptr[n], end = rowptr[n + 1];
        float a0 = 0.f, a1 = 0.f, a2 = 0.f, a3 = 0.f;
        for (int i = st; i < end; i += 16) {
            int2 e[8];
            float w[8];
#pragma unroll
            for (int j = 0; j < 8; j++) {          // this half's 8 edges (even/odd split)
                int idx = i + 2 * j + half;
                bool ok = idx < end;
                e[j] = csr[ok ? idx : st];
                w[j] = ok ? __int_as_float(e[j].y) : 0.f;
            }
            uint2 v[8];
#pragma unroll
            for (int j = 0; j < 8; j++)
                v[j] = h1u[(size_t)e[j].x * 32 + lc];
#pragma unroll
            for (int j = 0; j < 8; j++) {
                a0 = fmaf(w[j], bflo(v[j].x), a0);
                a1 = fmaf(w[j], bfhi(v[j].x), a1);
                a2 = fmaf(w[j], bflo(v[j].y), a2);
                a3 = fmaf(w[j], bfhi(v[j].y), a3);
            }
        }
        a0 += __shfl_xor(a0, 32); a1 += __shfl_xor(a1, 32);
        a2 += __shfl_xor(a2, 32); a3 += __shfl_xor(a3, 32);
        if (half == 0) {                            // lane lc owns cols 4lc..4lc+3
            uint2 p;
            p.x = packbf2(fmaxf(a0, 0.f), fmaxf(a1, 0.f));
            p.y = packbf2(fmaxf(a2, 0.f), fmaxf(a3, 0.f));
            *(uint2*)&aggs[wv * 4 + q][2 * lc] = p;
        }
    }
    __syncthreads();

    // MFMA: A = aggs[16][128] (LDS), B = w2 rows wv*16..wv*16+15 (L2)
    const int fr = lane & 15, fq = lane >> 4;
    f32x4 acc = (f32x4)0.f;
    const bf16_t* pb = w2b + (size_t)(wv * 16 + fr) * DH + fq * 8;
    const bf16_t* arow = (const bf16_t*)aggs[fr];
#pragma unroll
    for (int kk = 0; kk < 4; kk++) {
        bf16x8 af = *(const bf16x8*)&arow[kk * 32 + fq * 8];
        bf16x8 bf = *(const bf16x8*)(pb + kk * 32);
        acc = __builtin_amdgcn_mfma_f32_16x16x32_bf16(af, bf, acc, 0, 0, 0);
    }
#pragma unroll
    for (int j = 0; j < 4; j++) {
        int node = nb + fq * 4 + j;
        h2b[(size_t)node * DOUT + wv * 16 + fr] = (bf16_t)acc[j];
    }
}

// ---- SpMM d=64 + log_softmax: uint2 lanes, 4 rows/wave-load, 16 edges in flight ----
__global__ __launch_bounds__(256) void spmm64_ls_kernel(const int2* __restrict__ csr,
                                                        const int* __restrict__ rowptr,
                                                        const bf16_t* __restrict__ h2b,
                                                        float* __restrict__ outp) {
    int n = blockIdx.x * 4 + (threadIdx.x >> 6);
    int lane = threadIdx.x & 63;
    int g = lane >> 4, lg = lane & 15;     // 4 groups of 16 lanes; group g handles edge i+4j+g
    if (n >= NN) return;
    const uint2* h2u = (const uint2*)h2b;  // row = 16 uint2 (128 B)
    int st = rowptr[n], end = rowptr[n + 1];
    float a0 = 0.f, a1 = 0.f, a2 = 0.f, a3 = 0.f;
    for (int i = st; i < end; i += 16) {
        int2 e[4];
        float w[4];
#pragma unroll
        for (int j = 0; j < 4; j++) {
            int idx = i + 4 * j + g;
            bool ok = idx < end;
            e[j] = csr[ok ? idx : st];
            w[j] = ok ? __int_as_float(e[j].y) : 0.f;
        }
        uint2 v[4];
#pragma unroll
        for (int j = 0; j < 4; j++)
            v[j] = h2u[(size_t)e[j].x * 16 + lg];
#pragma unroll
        for (int j = 0; j < 4; j++) {
            a0 = fmaf(w[j], bflo(v[j].x), a0);
            a1 = fmaf(w[j], bfhi(v[j].x), a1);
            a2 = fmaf(w[j], bflo(v[j].y), a2);
            a3 = fmaf(w[j], bfhi(v[j].y), a3);
        }
    }
    // combine the 4 groups (lanes with equal lg then hold identical sums; cols 4lg..4lg+3)
    a0 += __shfl_xor(a0, 32); a1 += __shfl_xor(a1, 32);
    a2 += __shfl_xor(a2, 32); a3 += __shfl_xor(a3, 32);
    a0 += __shfl_xor(a0, 16); a1 += __shfl_xor(a1, 16);
    a2 += __shfl_xor(a2, 16); a3 += __shfl_xor(a3, 16);
    // log_softmax over 64 cols = 16 lanes x 4 cols
    float m = fmaxf(fmaxf(a0, a1), fmaxf(a2, a3));
#pragma unroll
    for (int off = 8; off >= 1; off >>= 1) m = fmaxf(m, __shfl_xor(m, off));
    float s = expf(a0 - m) + expf(a1 - m) + expf(a2 - m) + expf(a3 - m);
#pragma unroll
    for (int off = 8; off >= 1; off >>= 1) s += __shfl_xor(s, off);
    float ls = m + logf(s);
    if (lane < 16) {
        float4 o = make_float4(a0 - ls, a1 - ls, a2 - ls, a3 - ls);
        *(float4*)&outp[(size_t)n * DOUT + 4 * lg] = o;
    }
}

extern "C" void kernel_launch(void* const* d_in, const int* in_sizes, int n_in,
                              void* d_out, int out_size, void* d_ws, size_t ws_size,
                              hipStream_t stream) {
    const float* x  = (const float*)d_in[0];
    const float* w1 = (const float*)d_in[1];
    const float* w2 = (const float*)d_in[2];
    const int* esrc = (const int*)d_in[3];
    const int* edst = (const int*)d_in[4];
    const float* ew = (const float*)d_in[5];
    float* out = (float*)d_out;

    char* ws = (char*)d_ws;
    size_t off = 0;
    auto alloc = [&](size_t bytes) {
        void* p = ws + off;
        off = (off + bytes + 255) & ~(size_t)255;
        return p;
    };
    bf16_t* h1b      = (bf16_t*)alloc((size_t)NN * DH * 2);      // 25.6 MB
    bf16_t* h2b      = (bf16_t*)alloc((size_t)NN * DOUT * 2);    // 12.8 MB
    bf16_t* w1b      = (bf16_t*)alloc((size_t)DH * DIN * 2);
    bf16_t* w2b      = (bf16_t*)alloc((size_t)DOUT * DH * 2);
    int2*   csr      = (int2*)alloc((size_t)(NE + 16) * 8);      // 12.8 MB
    int2*   bsrcw    = (int2*)alloc((size_t)NE * 8);             // 12.8 MB
    unsigned short* bdst16 = (unsigned short*)alloc((size_t)NE * 2);
    int*    rowptr   = (int*)alloc((size_t)(NN + 1) * 4);
    int*    counts   = (int*)alloc((size_t)P1B * 256 * 4);
    int*    blockoffs= (int*)alloc((size_t)P1B * 256 * 4);
    int*    btotal   = (int*)alloc((size_t)256 * 4);
    int*    bbase    = (int*)alloc((size_t)256 * 4);

    // 0. weights -> bf16
    convert_w_kernel<<<(DH * DIN + 255) / 256, 256, 0, stream>>>(w1, w2, w1b, w2b);
    // 1. h1b = bf16(x) @ w1b^T   (LDS-staged MFMA)
    gemm1_mfma<<<(NN + 127) / 128, 256, 0, stream>>>(x, w1b, h1b);
    // 2. CSR build
    p1_count<<<P1B, 256, 0, stream>>>(edst, counts);
    p2_scanblocks<<<NB, 256, 0, stream>>>(counts, blockoffs, btotal);
    p3_scanbuckets<<<1, 256, 0, stream>>>(btotal, bbase, rowptr);
    p4_bucketwrite<<<P1B, 256, 0, stream>>>(esrc, edst, ew, blockoffs, bbase, bsrcw, bdst16);
    p5_bucketsort<<<NB, 256, 0, stream>>>(bsrcw, bdst16, bbase, btotal, csr, rowptr);
    // 3+4. h2b = relu(SpMM(h1b)) @ w2^T   (fused, MFMA epilogue)
    spmm1_fused<<<NN / 16, 256, 0, stream>>>(csr, rowptr, h1b, w2b, h2b);
    // 5. out = log_softmax(SpMM(h2b))
    spmm64_ls_kernel<<<(NN + 3) / 4, 256, 0, stream>>>(csr, rowptr, h2b, out);
}

// Round 11
// 240.281 us; speedup vs baseline: 8.0566x; 1.0670x over previous
//
#include <hip/hip_runtime.h>
#include <hip/hip_bf16.h>

#define NN 100000
#define NE 1600000
#define DIN 512
#define DH 128
#define DOUT 64

#define BSH 9                    // bucket = dst >> 9  (512 nodes per bucket)
#define NB ((NN + 511) / 512)    // 196 buckets
#define P1B 256                  // edge-partition blocks for count/write phases
#define EPB ((NE + P1B - 1) / P1B)  // 6250 edges per partition
#define SRCMASK 0x1FFFF          // NN < 2^17

typedef __bf16 bf16_t;
typedef __bf16 bf16x8 __attribute__((ext_vector_type(8)));
typedef float f32x4 __attribute__((ext_vector_type(4)));

__device__ __forceinline__ float bflo(unsigned v) { return __int_as_float(v << 16); }
__device__ __forceinline__ float bfhi(unsigned v) { return __int_as_float(v & 0xffff0000u); }
__device__ __forceinline__ unsigned packbf2(float a, float b) {
    unsigned short ua = __builtin_bit_cast(unsigned short, (bf16_t)a);
    unsigned short ub = __builtin_bit_cast(unsigned short, (bf16_t)b);
    return (unsigned)ua | ((unsigned)ub << 16);
}

// ---------------- weight conversion: w1,w2 -> bf16 ----------------
__global__ __launch_bounds__(256) void convert_w_kernel(const float* __restrict__ w1,
                                                        const float* __restrict__ w2,
                                                        bf16_t* __restrict__ w1b,
                                                        bf16_t* __restrict__ w2b) {
    int i = blockIdx.x * 256 + threadIdx.x;
    if (i < DH * DIN) w1b[i] = (bf16_t)w1[i];
    if (i < DOUT * DH) w2b[i] = (bf16_t)w2[i];
}

// ---------------- GEMM1: h1b[N,128] = bf16(x) @ w1b^T (LDS-staged MFMA) ----------------
__global__ __launch_bounds__(256) void gemm1_mfma(const float* __restrict__ x,
                                                  const bf16_t* __restrict__ w1b,
                                                  bf16_t* __restrict__ h1b) {
    __shared__ __align__(16) char AsB[128 * 128];
    __shared__ __align__(16) char BsB[128 * 128];
    const int t = threadIdx.x;
    const int wv = t >> 6, lane = t & 63;
    const int fr = lane & 15, fq = lane >> 4;
    const int rbase = blockIdx.x * 128;

    f32x4 acc[2][8];
#pragma unroll
    for (int m = 0; m < 2; m++)
#pragma unroll
        for (int n = 0; n < 8; n++) acc[m][n] = (f32x4)0.f;

    for (int k0 = 0; k0 < DIN; k0 += 64) {
#pragma unroll
        for (int j = 0; j < 4; j++) {
            int c = j * 256 + t;
            int row = c >> 3, k8 = c & 7;
            int gr = rbase + row;
            int grc = gr < NN ? gr : NN - 1;
            const float* src = x + (size_t)grc * DIN + k0 + k8 * 8;
            float4 a = *(const float4*)src;
            float4 b = *(const float4*)(src + 4);
            bf16x8 v;
            v[0] = (bf16_t)a.x; v[1] = (bf16_t)a.y; v[2] = (bf16_t)a.z; v[3] = (bf16_t)a.w;
            v[4] = (bf16_t)b.x; v[5] = (bf16_t)b.y; v[6] = (bf16_t)b.z; v[7] = (bf16_t)b.w;
            *(bf16x8*)&AsB[row * 128 + ((k8 ^ (row & 7)) * 16)] = v;
        }
#pragma unroll
        for (int i = 0; i < 4; i++) {
            int c = i * 256 + wv * 64 + lane;
            int cr = c >> 3, sp = c & 7;
            const bf16_t* gsrc = w1b + (size_t)cr * DIN + k0 + ((sp ^ (cr & 7)) * 8);
            __builtin_amdgcn_global_load_lds(
                (const __attribute__((address_space(1))) void*)gsrc,
                (__attribute__((address_space(3))) void*)(BsB + i * 4096 + wv * 1024),
                16, 0, 0);
        }
        __syncthreads();
#pragma unroll
        for (int kk = 0; kk < 2; kk++) {
            bf16x8 af[2];
#pragma unroll
            for (int m = 0; m < 2; m++) {
                int R = wv * 32 + m * 16 + fr;
                af[m] = *(const bf16x8*)&AsB[R * 128 + (((kk * 4 + fq) ^ (R & 7)) * 16)];
            }
#pragma unroll
            for (int n = 0; n < 8; n++) {
                int cr = n * 16 + fr;
                bf16x8 bf = *(const bf16x8*)&BsB[cr * 128 + (((kk * 4 + fq) ^ (cr & 7)) * 16)];
                acc[0][n] = __builtin_amdgcn_mfma_f32_16x16x32_bf16(af[0], bf, acc[0][n], 0, 0, 0);
                acc[1][n] = __builtin_amdgcn_mfma_f32_16x16x32_bf16(af[1], bf, acc[1][n], 0, 0, 0);
            }
        }
        __syncthreads();
    }
#pragma unroll
    for (int m = 0; m < 2; m++)
#pragma unroll
        for (int j = 0; j < 4; j++) {
            int row = rbase + wv * 32 + m * 16 + fq * 4 + j;
            if (row < NN) {
#pragma unroll
                for (int n = 0; n < 8; n++)
                    h1b[(size_t)row * DH + n * 16 + fr] = (bf16_t)acc[m][n][j];
            }
        }
}

// ================= CSR build: two-level counting sort (compressed) =================
__global__ __launch_bounds__(256) void p1_count(const int* __restrict__ edst,
                                                int* __restrict__ counts) {  // [P1B][256]
    __shared__ int h[NB];
    int blk = blockIdx.x, t = threadIdx.x;
    for (int i = t; i < NB; i += 256) h[i] = 0;
    __syncthreads();
    int e0 = blk * EPB, e1 = min(e0 + EPB, NE);
    for (int e = e0 + t; e < e1; e += 256) atomicAdd(&h[edst[e] >> BSH], 1);
    __syncthreads();
    for (int i = t; i < NB; i += 256) counts[blk * 256 + i] = h[i];
}

// per-bucket exclusive scan over the 256 edge-blocks (one partial per thread)
__global__ __launch_bounds__(256) void p2_scanblocks(const int* __restrict__ counts,
                                                     int* __restrict__ blockoffs,  // [P1B][256]
                                                     int* __restrict__ btotal) {   // [NB]
    __shared__ int s[256];
    int b = blockIdx.x, t = threadIdx.x;
    int c0 = counts[t * 256 + b];
    s[t] = c0;
    __syncthreads();
    for (int off = 1; off < 256; off <<= 1) {
        int v = (t >= off) ? s[t - off] : 0;
        __syncthreads();
        s[t] += v;
        __syncthreads();
    }
    blockoffs[t * 256 + b] = s[t] - c0;
    if (t == 255) btotal[b] = s[255];
}

__global__ __launch_bounds__(256) void p3_scanbuckets(const int* __restrict__ btotal,
                                                      int* __restrict__ bbase,
                                                      int* __restrict__ rowptr) {
    __shared__ int s[256];
    int t = threadIdx.x;
    int self = (t < NB) ? btotal[t] : 0;
    s[t] = self;
    __syncthreads();
    for (int off = 1; off < 256; off <<= 1) {
        int v = (t >= off) ? s[t - off] : 0;
        __syncthreads();
        s[t] += v;
        __syncthreads();
    }
    if (t < NB) bbase[t] = s[t] - self;
    if (t == 0) rowptr[NN] = NE;
}

// p4 packs dst&511 into bits [25:17] of the src word (src < 2^17) -> single int2 record
__global__ __launch_bounds__(256) void p4_bucketwrite(const int* __restrict__ esrc,
                                                      const int* __restrict__ edst,
                                                      const float* __restrict__ ew,
                                                      const int* __restrict__ blockoffs,
                                                      const int* __restrict__ bbase,
                                                      int2* __restrict__ bsrcw) {
    __shared__ int cur[NB];
    int blk = blockIdx.x, t = threadIdx.x;
    for (int i = t; i < NB; i += 256) cur[i] = bbase[i] + blockoffs[blk * 256 + i];
    __syncthreads();
    int e0 = blk * EPB, e1 = min(e0 + EPB, NE);
    for (int e = e0 + t; e < e1; e += 256) {
        int d = edst[e];
        int b = d >> BSH;
        int pos = atomicAdd(&cur[b], 1);
        bsrcw[pos] = make_int2(esrc[e] | ((d & 511) << 17), __float_as_int(ew[e]));
    }
}

__global__ __launch_bounds__(256) void p5_bucketsort(const int2* __restrict__ bsrcw,
                                                     const int* __restrict__ bbase,
                                                     const int* __restrict__ btotal,
                                                     int2* __restrict__ csr,
                                                     int* __restrict__ rowptr) {
    __shared__ int cnt[512];
    __shared__ int curs[512];
    __shared__ int sc[256];
    int b = blockIdx.x, t = threadIdx.x;
    int base = bbase[b], n = btotal[b];
    int node0 = b << BSH;
    cnt[t] = 0; cnt[t + 256] = 0;
    __syncthreads();
    for (int i = t; i < n; i += 256) {
        int d = (bsrcw[base + i].x >> 17) & 511;
        atomicAdd(&cnt[d], 1);
    }
    __syncthreads();
    int c0 = cnt[2 * t], c1 = cnt[2 * t + 1];
    sc[t] = c0 + c1;
    __syncthreads();
    for (int off = 1; off < 256; off <<= 1) {
        int v = (t >= off) ? sc[t - off] : 0;
        __syncthreads();
        sc[t] += v;
        __syncthreads();
    }
    int e0 = (t > 0) ? sc[t - 1] : 0;
    curs[2 * t] = e0;
    curs[2 * t + 1] = e0 + c0;
    int n0 = node0 + 2 * t, n1 = node0 + 2 * t + 1;
    if (n0 < NN) rowptr[n0] = base + e0;
    if (n1 < NN) rowptr[n1] = base + e0 + c0;
    __syncthreads();
    for (int i = t; i < n; i += 256) {
        int2 sw = bsrcw[base + i];
        int d = (sw.x >> 17) & 511;
        int p = atomicAdd(&curs[d], 1);
        csr[base + p] = sw;          // keep packed; consumers mask with SRCMASK
    }
}

// ---- fused: spmm128 gather (uint2 lanes: 2 rows/wave-load, 16 edges in flight) + relu + MFMA ----
__global__ __launch_bounds__(256) void spmm1_fused(const int2* __restrict__ csr,
                                                   const int* __restrict__ rowptr,
                                                   const bf16_t* __restrict__ h1b,
                                                   const bf16_t* __restrict__ w2b,
                                                   bf16_t* __restrict__ h2b) {
    __shared__ unsigned aggs[16][68];   // [node][k-pair], stride 68 dwords
    const int t = threadIdx.x;
    const int wv = t >> 6, lane = t & 63;
    const int half = lane >> 5, lc = lane & 31;
    const int nb = blockIdx.x * 16;     // NN % 16 == 0
    const uint2* h1u = (const uint2*)h1b;   // row = 32 uint2 (256 B)

#pragma unroll
    for (int q = 0; q < 4; q++) {
        int n = nb + wv * 4 + q;
        int st = rowptr[n], end = rowptr[n + 1];
        float a0 = 0.f, a1 = 0.f, a2 = 0.f, a3 = 0.f;
        for (int i = st; i < end; i += 16) {
            int2 e[8];
            float w[8];
#pragma unroll
            for (int j = 0; j < 8; j++) {          // this half's 8 edges (even/odd split)
                int idx = i + 2 * j + half;
                bool ok = idx < end;
                e[j] = csr[ok ? idx : st];
                w[j] = ok ? __int_as_float(e[j].y) : 0.f;
            }
            uint2 v[8];
#pragma unroll
            for (int j = 0; j < 8; j++)
                v[j] = h1u[(size_t)(e[j].x & SRCMASK) * 32 + lc];
#pragma unroll
            for (int j = 0; j < 8; j++) {
                a0 = fmaf(w[j], bflo(v[j].x), a0);
                a1 = fmaf(w[j], bfhi(v[j].x), a1);
                a2 = fmaf(w[j], bflo(v[j].y), a2);
                a3 = fmaf(w[j], bfhi(v[j].y), a3);
            }
        }
        a0 += __shfl_xor(a0, 32); a1 += __shfl_xor(a1, 32);
        a2 += __shfl_xor(a2, 32); a3 += __shfl_xor(a3, 32);
        if (half == 0) {                            // lane lc owns cols 4lc..4lc+3
            uint2 p;
            p.x = packbf2(fmaxf(a0, 0.f), fmaxf(a1, 0.f));
            p.y = packbf2(fmaxf(a2, 0.f), fmaxf(a3, 0.f));
            *(uint2*)&aggs[wv * 4 + q][2 * lc] = p;
        }
    }
    __syncthreads();

    // MFMA: A = aggs[16][128] (LDS), B = w2 rows wv*16..wv*16+15 (L2)
    const int fr = lane & 15, fq = lane >> 4;
    f32x4 acc = (f32x4)0.f;
    const bf16_t* pb = w2b + (size_t)(wv * 16 + fr) * DH + fq * 8;
    const bf16_t* arow = (const bf16_t*)aggs[fr];
#pragma unroll
    for (int kk = 0; kk < 4; kk++) {
        bf16x8 af = *(const bf16x8*)&arow[kk * 32 + fq * 8];
        bf16x8 bf = *(const bf16x8*)(pb + kk * 32);
        acc = __builtin_amdgcn_mfma_f32_16x16x32_bf16(af, bf, acc, 0, 0, 0);
    }
#pragma unroll
    for (int j = 0; j < 4; j++) {
        int node = nb + fq * 4 + j;
        h2b[(size_t)node * DOUT + wv * 16 + fr] = (bf16_t)acc[j];
    }
}

// ---- SpMM d=64 + log_softmax: uint2 lanes, 4 rows/wave-load, 16 edges in flight ----
__global__ __launch_bounds__(256) void spmm64_ls_kernel(const int2* __restrict__ csr,
                                                        const int* __restrict__ rowptr,
                                                        const bf16_t* __restrict__ h2b,
                                                        float* __restrict__ outp) {
    int n = blockIdx.x * 4 + (threadIdx.x >> 6);
    int lane = threadIdx.x & 63;
    int g = lane >> 4, lg = lane & 15;     // 4 groups of 16 lanes; group g handles edge i+4j+g
    if (n >= NN) return;
    const uint2* h2u = (const uint2*)h2b;  // row = 16 uint2 (128 B)
    int st = rowptr[n], end = rowptr[n + 1];
    float a0 = 0.f, a1 = 0.f, a2 = 0.f, a3 = 0.f;
    for (int i = st; i < end; i += 16) {
        int2 e[4];
        float w[4];
#pragma unroll
        for (int j = 0; j < 4; j++) {
            int idx = i + 4 * j + g;
            bool ok = idx < end;
            e[j] = csr[ok ? idx : st];
            w[j] = ok ? __int_as_float(e[j].y) : 0.f;
        }
        uint2 v[4];
#pragma unroll
        for (int j = 0; j < 4; j++)
            v[j] = h2u[(size_t)(e[j].x & SRCMASK) * 16 + lg];
#pragma unroll
        for (int j = 0; j < 4; j++) {
            a0 = fmaf(w[j], bflo(v[j].x), a0);
            a1 = fmaf(w[j], bfhi(v[j].x), a1);
            a2 = fmaf(w[j], bflo(v[j].y), a2);
            a3 = fmaf(w[j], bfhi(v[j].y), a3);
        }
    }
    // combine the 4 groups (lanes with equal lg then hold identical sums; cols 4lg..4lg+3)
    a0 += __shfl_xor(a0, 32); a1 += __shfl_xor(a1, 32);
    a2 += __shfl_xor(a2, 32); a3 += __shfl_xor(a3, 32);
    a0 += __shfl_xor(a0, 16); a1 += __shfl_xor(a1, 16);
    a2 += __shfl_xor(a2, 16); a3 += __shfl_xor(a3, 16);
    // log_softmax over 64 cols = 16 lanes x 4 cols
    float m = fmaxf(fmaxf(a0, a1), fmaxf(a2, a3));
#pragma unroll
    for (int off = 8; off >= 1; off >>= 1) m = fmaxf(m, __shfl_xor(m, off));
    float s = expf(a0 - m) + expf(a1 - m) + expf(a2 - m) + expf(a3 - m);
#pragma unroll
    for (int off = 8; off >= 1; off >>= 1) s += __shfl_xor(s, off);
    float ls = m + logf(s);
    if (lane < 16) {
        float4 o = make_float4(a0 - ls, a1 - ls, a2 - ls, a3 - ls);
        *(float4*)&outp[(size_t)n * DOUT + 4 * lg] = o;
    }
}

extern "C" void kernel_launch(void* const* d_in, const int* in_sizes, int n_in,
                              void* d_out, int out_size, void* d_ws, size_t ws_size,
                              hipStream_t stream) {
    const float* x  = (const float*)d_in[0];
    const float* w1 = (const float*)d_in[1];
    const float* w2 = (const float*)d_in[2];
    const int* esrc = (const int*)d_in[3];
    const int* edst = (const int*)d_in[4];
    const float* ew = (const float*)d_in[5];
    float* out = (float*)d_out;

    char* ws = (char*)d_ws;
    size_t off = 0;
    auto alloc = [&](size_t bytes) {
        void* p = ws + off;
        off = (off + bytes + 255) & ~(size_t)255;
        return p;
    };
    bf16_t* h1b      = (bf16_t*)alloc((size_t)NN * DH * 2);      // 25.6 MB
    bf16_t* h2b      = (bf16_t*)alloc((size_t)NN * DOUT * 2);    // 12.8 MB
    bf16_t* w1b      = (bf16_t*)alloc((size_t)DH * DIN * 2);
    bf16_t* w2b      = (bf16_t*)alloc((size_t)DOUT * DH * 2);
    int2*   csr      = (int2*)alloc((size_t)(NE + 16) * 8);      // 12.8 MB
    int2*   bsrcw    = (int2*)alloc((size_t)NE * 8);             // 12.8 MB
    int*    rowptr   = (int*)alloc((size_t)(NN + 1) * 4);
    int*    counts   = (int*)alloc((size_t)P1B * 256 * 4);       // 256 KB
    int*    blockoffs= (int*)alloc((size_t)P1B * 256 * 4);       // 256 KB
    int*    btotal   = (int*)alloc((size_t)256 * 4);
    int*    bbase    = (int*)alloc((size_t)256 * 4);

    // 0. weights -> bf16
    convert_w_kernel<<<(DH * DIN + 255) / 256, 256, 0, stream>>>(w1, w2, w1b, w2b);
    // 1. h1b = bf16(x) @ w1b^T   (LDS-staged MFMA)
    gemm1_mfma<<<(NN + 127) / 128, 256, 0, stream>>>(x, w1b, h1b);
    // 2. CSR build (dst-sorted; packed records)
    p1_count<<<P1B, 256, 0, stream>>>(edst, counts);
    p2_scanblocks<<<NB, 256, 0, stream>>>(counts, blockoffs, btotal);
    p3_scanbuckets<<<1, 256, 0, stream>>>(btotal, bbase, rowptr);
    p4_bucketwrite<<<P1B, 256, 0, stream>>>(esrc, edst, ew, blockoffs, bbase, bsrcw);
    p5_bucketsort<<<NB, 256, 0, stream>>>(bsrcw, bbase, btotal, csr, rowptr);
    // 3+4. h2b = relu(SpMM(h1b)) @ w2^T   (fused, MFMA epilogue)
    spmm1_fused<<<NN / 16, 256, 0, stream>>>(csr, rowptr, h1b, w2b, h2b);
    // 5. out = log_softmax(SpMM(h2b))
    spmm64_ls_kernel<<<(NN + 3) / 4, 256, 0, stream>>>(csr, rowptr, h2b, out);
}

// Round 12
// 229.362 us; speedup vs baseline: 8.4402x; 1.0476x over previous
//
#include <hip/hip_runtime.h>
#include <hip/hip_bf16.h>

#define NN 100000
#define NE 1600000
#define DIN 512
#define DH 128
#define DOUT 64

#define BSH 9                    // bucket = dst >> 9  (512 nodes per bucket)
#define NB ((NN + 511) / 512)    // 196 buckets
#define P1B 256                  // edge-partition blocks for count/write phases
#define EPB ((NE + P1B - 1) / P1B)  // 6250 edges per partition
#define SRCMASK 0x1FFFF          // NN < 2^17
#define NGB ((NN + 127) / 128)   // 782 gemm1 tiles

typedef __bf16 bf16_t;
typedef __bf16 bf16x8 __attribute__((ext_vector_type(8)));
typedef float f32x4 __attribute__((ext_vector_type(4)));

__device__ __forceinline__ float bflo(unsigned v) { return __int_as_float(v << 16); }
__device__ __forceinline__ float bfhi(unsigned v) { return __int_as_float(v & 0xffff0000u); }
__device__ __forceinline__ unsigned packbf2(float a, float b) {
    unsigned short ua = __builtin_bit_cast(unsigned short, (bf16_t)a);
    unsigned short ub = __builtin_bit_cast(unsigned short, (bf16_t)b);
    return (unsigned)ua | ((unsigned)ub << 16);
}

// ---- kernel A: weight convert (blocks [0,256)) + p1 edge-bucket histogram (blocks [256,512)) ----
__global__ __launch_bounds__(256) void convert_p1_kernel(const float* __restrict__ w1,
                                                         const float* __restrict__ w2,
                                                         bf16_t* __restrict__ w1b,
                                                         bf16_t* __restrict__ w2b,
                                                         const int* __restrict__ edst,
                                                         int* __restrict__ counts) {
    const int t = threadIdx.x;
    if (blockIdx.x < 256) {
        int i = blockIdx.x * 256 + t;
        if (i < DH * DIN) w1b[i] = (bf16_t)w1[i];
        if (i < DOUT * DH) w2b[i] = (bf16_t)w2[i];
    } else {
        __shared__ int h[NB];
        int blk = blockIdx.x - 256;
        for (int i = t; i < NB; i += 256) h[i] = 0;
        __syncthreads();
        int e0 = blk * EPB, e1 = min(e0 + EPB, NE);
        for (int e = e0 + t; e < e1; e += 256) atomicAdd(&h[edst[e] >> BSH], 1);
        __syncthreads();
        for (int i = t; i < NB; i += 256) counts[blk * 256 + i] = h[i];
    }
}

// ---- kernel B: gemm1 (blocks [0,NGB)) + p2 per-bucket scan over edge-blocks (blocks [NGB,NGB+NB)) ----
__global__ __launch_bounds__(256) void gemm1_p2_kernel(const float* __restrict__ x,
                                                       const bf16_t* __restrict__ w1b,
                                                       bf16_t* __restrict__ h1b,
                                                       const int* __restrict__ counts,
                                                       int* __restrict__ blockoffs,
                                                       int* __restrict__ btotal) {
    const int t = threadIdx.x;
    if (blockIdx.x >= NGB) {
        // ---- p2 path ----
        __shared__ int s2[256];
        int b = blockIdx.x - NGB;
        int c0 = counts[t * 256 + b];
        s2[t] = c0;
        __syncthreads();
        for (int off = 1; off < 256; off <<= 1) {
            int v = (t >= off) ? s2[t - off] : 0;
            __syncthreads();
            s2[t] += v;
            __syncthreads();
        }
        blockoffs[t * 256 + b] = s2[t] - c0;
        if (t == 255) btotal[b] = s2[255];
        return;
    }
    // ---- gemm1 path (LDS-staged MFMA) ----
    __shared__ __align__(16) char AsB[128 * 128];
    __shared__ __align__(16) char BsB[128 * 128];
    const int wv = t >> 6, lane = t & 63;
    const int fr = lane & 15, fq = lane >> 4;
    const int rbase = blockIdx.x * 128;

    f32x4 acc[2][8];
#pragma unroll
    for (int m = 0; m < 2; m++)
#pragma unroll
        for (int n = 0; n < 8; n++) acc[m][n] = (f32x4)0.f;

    for (int k0 = 0; k0 < DIN; k0 += 64) {
#pragma unroll
        for (int j = 0; j < 4; j++) {
            int c = j * 256 + t;
            int row = c >> 3, k8 = c & 7;
            int gr = rbase + row;
            int grc = gr < NN ? gr : NN - 1;
            const float* src = x + (size_t)grc * DIN + k0 + k8 * 8;
            float4 a = *(const float4*)src;
            float4 b = *(const float4*)(src + 4);
            bf16x8 v;
            v[0] = (bf16_t)a.x; v[1] = (bf16_t)a.y; v[2] = (bf16_t)a.z; v[3] = (bf16_t)a.w;
            v[4] = (bf16_t)b.x; v[5] = (bf16_t)b.y; v[6] = (bf16_t)b.z; v[7] = (bf16_t)b.w;
            *(bf16x8*)&AsB[row * 128 + ((k8 ^ (row & 7)) * 16)] = v;
        }
#pragma unroll
        for (int i = 0; i < 4; i++) {
            int c = i * 256 + wv * 64 + lane;
            int cr = c >> 3, sp = c & 7;
            const bf16_t* gsrc = w1b + (size_t)cr * DIN + k0 + ((sp ^ (cr & 7)) * 8);
            __builtin_amdgcn_global_load_lds(
                (const __attribute__((address_space(1))) void*)gsrc,
                (__attribute__((address_space(3))) void*)(BsB + i * 4096 + wv * 1024),
                16, 0, 0);
        }
        __syncthreads();
#pragma unroll
        for (int kk = 0; kk < 2; kk++) {
            bf16x8 af[2];
#pragma unroll
            for (int m = 0; m < 2; m++) {
                int R = wv * 32 + m * 16 + fr;
                af[m] = *(const bf16x8*)&AsB[R * 128 + (((kk * 4 + fq) ^ (R & 7)) * 16)];
            }
#pragma unroll
            for (int n = 0; n < 8; n++) {
                int cr = n * 16 + fr;
                bf16x8 bf = *(const bf16x8*)&BsB[cr * 128 + (((kk * 4 + fq) ^ (cr & 7)) * 16)];
                acc[0][n] = __builtin_amdgcn_mfma_f32_16x16x32_bf16(af[0], bf, acc[0][n], 0, 0, 0);
                acc[1][n] = __builtin_amdgcn_mfma_f32_16x16x32_bf16(af[1], bf, acc[1][n], 0, 0, 0);
            }
        }
        __syncthreads();
    }
#pragma unroll
    for (int m = 0; m < 2; m++)
#pragma unroll
        for (int j = 0; j < 4; j++) {
            int row = rbase + wv * 32 + m * 16 + fq * 4 + j;
            if (row < NN) {
#pragma unroll
                for (int n = 0; n < 8; n++)
                    h1b[(size_t)row * DH + n * 16 + fr] = (bf16_t)acc[m][n][j];
            }
        }
}

// ---- p4: bucket-grouped write; every block recomputes bucket bases from btotal (inline p3) ----
// block 0 publishes bbase + rowptr[NN] for p5.
__global__ __launch_bounds__(256) void p4_bucketwrite(const int* __restrict__ esrc,
                                                      const int* __restrict__ edst,
                                                      const float* __restrict__ ew,
                                                      const int* __restrict__ blockoffs,
                                                      const int* __restrict__ btotal,
                                                      int* __restrict__ bbase_g,
                                                      int* __restrict__ rowptr,
                                                      int2* __restrict__ bsrcw) {
    __shared__ int s[256];
    __shared__ int cur[NB];
    int blk = blockIdx.x, t = threadIdx.x;
    int self = (t < NB) ? btotal[t] : 0;
    s[t] = self;
    __syncthreads();
    for (int off = 1; off < 256; off <<= 1) {
        int v = (t >= off) ? s[t - off] : 0;
        __syncthreads();
        s[t] += v;
        __syncthreads();
    }
    if (t < NB) {
        int base = s[t] - self;
        cur[t] = base + blockoffs[blk * 256 + t];
        if (blk == 0) bbase_g[t] = base;
    }
    if (blk == 0 && t == 0) rowptr[NN] = NE;
    __syncthreads();
    int e0 = blk * EPB, e1 = min(e0 + EPB, NE);
    for (int e = e0 + t; e < e1; e += 256) {
        int d = edst[e];
        int b = d >> BSH;
        int pos = atomicAdd(&cur[b], 1);
        bsrcw[pos] = make_int2(esrc[e] | ((d & 511) << 17), __float_as_int(ew[e]));
    }
}

__global__ __launch_bounds__(256) void p5_bucketsort(const int2* __restrict__ bsrcw,
                                                     const int* __restrict__ bbase,
                                                     const int* __restrict__ btotal,
                                                     int2* __restrict__ csr,
                                                     int* __restrict__ rowptr) {
    __shared__ int cnt[512];
    __shared__ int curs[512];
    __shared__ int sc[256];
    int b = blockIdx.x, t = threadIdx.x;
    int base = bbase[b], n = btotal[b];
    int node0 = b << BSH;
    cnt[t] = 0; cnt[t + 256] = 0;
    __syncthreads();
    for (int i = t; i < n; i += 256) {
        int d = (bsrcw[base + i].x >> 17) & 511;
        atomicAdd(&cnt[d], 1);
    }
    __syncthreads();
    int c0 = cnt[2 * t], c1 = cnt[2 * t + 1];
    sc[t] = c0 + c1;
    __syncthreads();
    for (int off = 1; off < 256; off <<= 1) {
        int v = (t >= off) ? sc[t - off] : 0;
        __syncthreads();
        sc[t] += v;
        __syncthreads();
    }
    int e0 = (t > 0) ? sc[t - 1] : 0;
    curs[2 * t] = e0;
    curs[2 * t + 1] = e0 + c0;
    int n0 = node0 + 2 * t, n1 = node0 + 2 * t + 1;
    if (n0 < NN) rowptr[n0] = base + e0;
    if (n1 < NN) rowptr[n1] = base + e0 + c0;
    __syncthreads();
    for (int i = t; i < n; i += 256) {
        int2 sw = bsrcw[base + i];
        int d = (sw.x >> 17) & 511;
        int p = atomicAdd(&curs[d], 1);
        csr[base + p] = sw;          // keep packed; consumers mask with SRCMASK
    }
}

// ---- fused: spmm128 gather (uint2 lanes: 2 rows/wave-load, 16 edges in flight) + relu + MFMA ----
__global__ __launch_bounds__(256) void spmm1_fused(const int2* __restrict__ csr,
                                                   const int* __restrict__ rowptr,
                                                   const bf16_t* __restrict__ h1b,
                                                   const bf16_t* __restrict__ w2b,
                                                   bf16_t* __restrict__ h2b) {
    __shared__ unsigned aggs[16][68];   // [node][k-pair], stride 68 dwords
    const int t = threadIdx.x;
    const int wv = t >> 6, lane = t & 63;
    const int half = lane >> 5, lc = lane & 31;
    const int nb = blockIdx.x * 16;     // NN % 16 == 0
    const uint2* h1u = (const uint2*)h1b;   // row = 32 uint2 (256 B)

#pragma unroll
    for (int q = 0; q < 4; q++) {
        int n = nb + wv * 4 + q;
        int st = rowptr[n], end = rowptr[n + 1];
        float a0 = 0.f, a1 = 0.f, a2 = 0.f, a3 = 0.f;
        for (int i = st; i < end; i += 16) {
            int2 e[8];
            float w[8];
#pragma unroll
            for (int j = 0; j < 8; j++) {          // this half's 8 edges (even/odd split)
                int idx = i + 2 * j + half;
                bool ok = idx < end;
                e[j] = csr[ok ? idx : st];
                w[j] = ok ? __int_as_float(e[j].y) : 0.f;
            }
            uint2 v[8];
#pragma unroll
            for (int j = 0; j < 8; j++)
                v[j] = h1u[(size_t)(e[j].x & SRCMASK) * 32 + lc];
#pragma unroll
            for (int j = 0; j < 8; j++) {
                a0 = fmaf(w[j], bflo(v[j].x), a0);
                a1 = fmaf(w[j], bfhi(v[j].x), a1);
                a2 = fmaf(w[j], bflo(v[j].y), a2);
                a3 = fmaf(w[j], bfhi(v[j].y), a3);
            }
        }
        a0 += __shfl_xor(a0, 32); a1 += __shfl_xor(a1, 32);
        a2 += __shfl_xor(a2, 32); a3 += __shfl_xor(a3, 32);
        if (half == 0) {                            // lane lc owns cols 4lc..4lc+3
            uint2 p;
            p.x = packbf2(fmaxf(a0, 0.f), fmaxf(a1, 0.f));
            p.y = packbf2(fmaxf(a2, 0.f), fmaxf(a3, 0.f));
            *(uint2*)&aggs[wv * 4 + q][2 * lc] = p;
        }
    }
    __syncthreads();

    // MFMA: A = aggs[16][128] (LDS), B = w2 rows wv*16..wv*16+15 (L2)
    const int fr = lane & 15, fq = lane >> 4;
    f32x4 acc = (f32x4)0.f;
    const bf16_t* pb = w2b + (size_t)(wv * 16 + fr) * DH + fq * 8;
    const bf16_t* arow = (const bf16_t*)aggs[fr];
#pragma unroll
    for (int kk = 0; kk < 4; kk++) {
        bf16x8 af = *(const bf16x8*)&arow[kk * 32 + fq * 8];
        bf16x8 bf = *(const bf16x8*)(pb + kk * 32);
        acc = __builtin_amdgcn_mfma_f32_16x16x32_bf16(af, bf, acc, 0, 0, 0);
    }
#pragma unroll
    for (int j = 0; j < 4; j++) {
        int node = nb + fq * 4 + j;
        h2b[(size_t)node * DOUT + wv * 16 + fr] = (bf16_t)acc[j];
    }
}

// ---- SpMM d=64 + log_softmax: uint2 lanes, 4 rows/wave-load, 16 edges in flight ----
__global__ __launch_bounds__(256) void spmm64_ls_kernel(const int2* __restrict__ csr,
                                                        const int* __restrict__ rowptr,
                                                        const bf16_t* __restrict__ h2b,
                                                        float* __restrict__ outp) {
    int n = blockIdx.x * 4 + (threadIdx.x >> 6);
    int lane = threadIdx.x & 63;
    int g = lane >> 4, lg = lane & 15;     // 4 groups of 16 lanes; group g handles edge i+4j+g
    if (n >= NN) return;
    const uint2* h2u = (const uint2*)h2b;  // row = 16 uint2 (128 B)
    int st = rowptr[n], end = rowptr[n + 1];
    float a0 = 0.f, a1 = 0.f, a2 = 0.f, a3 = 0.f;
    for (int i = st; i < end; i += 16) {
        int2 e[4];
        float w[4];
#pragma unroll
        for (int j = 0; j < 4; j++) {
            int idx = i + 4 * j + g;
            bool ok = idx < end;
            e[j] = csr[ok ? idx : st];
            w[j] = ok ? __int_as_float(e[j].y) : 0.f;
        }
        uint2 v[4];
#pragma unroll
        for (int j = 0; j < 4; j++)
            v[j] = h2u[(size_t)(e[j].x & SRCMASK) * 16 + lg];
#pragma unroll
        for (int j = 0; j < 4; j++) {
            a0 = fmaf(w[j], bflo(v[j].x), a0);
            a1 = fmaf(w[j], bfhi(v[j].x), a1);
            a2 = fmaf(w[j], bflo(v[j].y), a2);
            a3 = fmaf(w[j], bfhi(v[j].y), a3);
        }
    }
    // combine the 4 groups (lanes with equal lg then hold identical sums; cols 4lg..4lg+3)
    a0 += __shfl_xor(a0, 32); a1 += __shfl_xor(a1, 32);
    a2 += __shfl_xor(a2, 32); a3 += __shfl_xor(a3, 32);
    a0 += __shfl_xor(a0, 16); a1 += __shfl_xor(a1, 16);
    a2 += __shfl_xor(a2, 16); a3 += __shfl_xor(a3, 16);
    // log_softmax over 64 cols = 16 lanes x 4 cols
    float m = fmaxf(fmaxf(a0, a1), fmaxf(a2, a3));
#pragma unroll
    for (int off = 8; off >= 1; off >>= 1) m = fmaxf(m, __shfl_xor(m, off));
    float s = expf(a0 - m) + expf(a1 - m) + expf(a2 - m) + expf(a3 - m);
#pragma unroll
    for (int off = 8; off >= 1; off >>= 1) s += __shfl_xor(s, off);
    float ls = m + logf(s);
    if (lane < 16) {
        float4 o = make_float4(a0 - ls, a1 - ls, a2 - ls, a3 - ls);
        *(float4*)&outp[(size_t)n * DOUT + 4 * lg] = o;
    }
}

extern "C" void kernel_launch(void* const* d_in, const int* in_sizes, int n_in,
                              void* d_out, int out_size, void* d_ws, size_t ws_size,
                              hipStream_t stream) {
    const float* x  = (const float*)d_in[0];
    const float* w1 = (const float*)d_in[1];
    const float* w2 = (const float*)d_in[2];
    const int* esrc = (const int*)d_in[3];
    const int* edst = (const int*)d_in[4];
    const float* ew = (const float*)d_in[5];
    float* out = (float*)d_out;

    char* ws = (char*)d_ws;
    size_t off = 0;
    auto alloc = [&](size_t bytes) {
        void* p = ws + off;
        off = (off + bytes + 255) & ~(size_t)255;
        return p;
    };
    bf16_t* h1b      = (bf16_t*)alloc((size_t)NN * DH * 2);      // 25.6 MB
    bf16_t* h2b      = (bf16_t*)alloc((size_t)NN * DOUT * 2);    // 12.8 MB
    bf16_t* w1b      = (bf16_t*)alloc((size_t)DH * DIN * 2);
    bf16_t* w2b      = (bf16_t*)alloc((size_t)DOUT * DH * 2);
    int2*   csr      = (int2*)alloc((size_t)(NE + 16) * 8);      // 12.8 MB
    int2*   bsrcw    = (int2*)alloc((size_t)NE * 8);             // 12.8 MB
    int*    rowptr   = (int*)alloc((size_t)(NN + 1) * 4);
    int*    counts   = (int*)alloc((size_t)P1B * 256 * 4);       // 256 KB
    int*    blockoffs= (int*)alloc((size_t)P1B * 256 * 4);       // 256 KB
    int*    btotal   = (int*)alloc((size_t)256 * 4);
    int*    bbase    = (int*)alloc((size_t)256 * 4);

    // A. weights -> bf16  ||  p1 edge-bucket histogram
    convert_p1_kernel<<<512, 256, 0, stream>>>(w1, w2, w1b, w2b, edst, counts);
    // B. gemm1 (h1b = bf16(x) @ w1b^T)  ||  p2 per-bucket scan
    gemm1_p2_kernel<<<NGB + NB, 256, 0, stream>>>(x, w1b, h1b, counts, blockoffs, btotal);
    // p4 (inline p3 scan; block 0 publishes bbase + rowptr[NN])
    p4_bucketwrite<<<P1B, 256, 0, stream>>>(esrc, edst, ew, blockoffs, btotal, bbase, rowptr, bsrcw);
    // p5: in-bucket counting sort -> csr + rowptr
    p5_bucketsort<<<NB, 256, 0, stream>>>(bsrcw, bbase, btotal, csr, rowptr);
    // spmm1 + relu + gemm2 (MFMA epilogue)
    spmm1_fused<<<NN / 16, 256, 0, stream>>>(csr, rowptr, h1b, w2b, h2b);
    // spmm2 + log_softmax
    spmm64_ls_kernel<<<(NN + 3) / 4, 256, 0, stream>>>(csr, rowptr, h2b, out);
}